// Round 1
// baseline (3042.832 us; speedup 1.0000x reference)
//
#include <hip/hip_runtime.h>

#define N_NODES 4096
#define H_DIM 32
#define F_INPUT 5
#define ROLLS 200

typedef __attribute__((ext_vector_type(8))) short bf16x8;
typedef __attribute__((ext_vector_type(4))) float fx4;
typedef __attribute__((ext_vector_type(4))) unsigned short us4;

__device__ __forceinline__ unsigned short f2bf(float f) {
  unsigned int u = __builtin_bit_cast(unsigned int, f);
  u += 0x7fffu + ((u >> 16) & 1u);   // round-to-nearest-even (inputs are benign, no NaN/inf)
  return (unsigned short)(u >> 16);
}

// ---- init: A fp32 -> bf16 (one-time per call; A is L3-resident afterwards) ----
__global__ void k_convA(const float* __restrict__ A, unsigned short* __restrict__ Abf) {
  size_t i = (size_t)blockIdx.x * blockDim.x + threadIdx.x;
  const size_t stride = (size_t)gridDim.x * blockDim.x;
  const size_t n4 = (size_t)N_NODES * N_NODES / 4;
  for (; i < n4; i += stride) {
    fx4 v = ((const fx4*)A)[i];
    us4 o;
    o.x = f2bf(v.x); o.y = f2bf(v.y); o.z = f2bf(v.z); o.w = f2bf(v.w);
    ((us4*)Abf)[i] = o;
  }
}

// ---- init: h=c=0, Mt0 = (x0 @ Wx)^T as bf16, weight conversions ----
__global__ void k_init(const float* __restrict__ X, const float* __restrict__ Wx,
                       const float* __restrict__ Wih, const float* __restrict__ Whh,
                       const float* __restrict__ Wh, const float* __restrict__ Wc,
                       unsigned short* __restrict__ Mt0, float* __restrict__ h, float* __restrict__ c,
                       unsigned short* __restrict__ WihB, unsigned short* __restrict__ WhhB,
                       unsigned short* __restrict__ WhT, unsigned short* __restrict__ WcT) {
  int idx = blockIdx.x * 256 + threadIdx.x;      // grid 512*256 = 131072 = N*H exactly
  h[idx] = 0.f;
  c[idx] = 0.f;
  int k = idx >> 12;         // 0..31
  int row = idx & 4095;      // coalesced Mt writes
  float s = 0.f;
#pragma unroll
  for (int f = 0; f < F_INPUT; ++f) s += X[row * F_INPUT + f] * Wx[f * H_DIM + k];
  Mt0[(size_t)k * N_NODES + row] = f2bf(s);
  if (idx < 4096) { WihB[idx] = f2bf(Wih[idx]); WhhB[idx] = f2bf(Whh[idx]); }
  if (idx < 1024) {
    int a = idx >> 5, b = idx & 31;
    WhT[a * 32 + b] = f2bf(Wh[b * 32 + a]);   // WhT[n][j] = Wh[j][n]
    WcT[a * 32 + b] = f2bf(Wc[b * 32 + a]);
  }
}

// ---- one recurrence step: inp = A@M ; gates ; LSTM ; M_next (transposed bf16) ----
// block = 512 threads (8 waves), 16 rows per block, grid = 256
__global__ __launch_bounds__(512, 1) void k_step(
    const unsigned short* __restrict__ Abf,
    const unsigned short* __restrict__ MtIn,
    unsigned short* __restrict__ MtOut,
    float* __restrict__ h, float* __restrict__ c,
    const unsigned short* __restrict__ WihB, const unsigned short* __restrict__ WhhB,
    const unsigned short* __restrict__ WhT, const unsigned short* __restrict__ WcT,
    const float* __restrict__ Xn, const float* __restrict__ Wx,
    const float* __restrict__ b_ih, const float* __restrict__ b_hh,
    const float* __restrict__ Wfc, const float* __restrict__ b_fc,
    float* __restrict__ out, int last) {

  __shared__ __align__(16) float red[8 * 16 * 33];            // split-K partials (pad 33 vs bank conflicts)
  __shared__ __align__(16) unsigned short inpB[16 * 48];      // inp bf16, A-frag layout (row stride 96B, 16B-aligned)
  __shared__ __align__(16) unsigned short hB[16 * 48];
  __shared__ __align__(16) unsigned short hnB[16 * 48];
  __shared__ __align__(16) unsigned short cnB[16 * 48];
  __shared__ __align__(16) unsigned short MnB[16 * 48];
  __shared__ __align__(16) float gatesLds[16 * 132];
  __shared__ __align__(16) float xLds[16 * 8];

  const int tid  = threadIdx.x;
  const int wave = tid >> 6;        // 0..7
  const int lane = tid & 63;
  const int l15  = lane & 15;
  const int quad = lane >> 4;       // 0..3
  const int row0 = blockIdx.x << 4;

  // stage h_t tile (bf16, A-frag layout) and x_{t+1} tile
  { int r = tid >> 5, k = tid & 31;
    hB[r * 48 + k] = f2bf(h[(size_t)(row0 + r) * H_DIM + k]); }
  if (!last && tid < 128) {
    int r = tid >> 3, f = tid & 7;
    if (f < F_INPUT) xLds[r * 8 + f] = Xn[(size_t)(row0 + r) * F_INPUT + f];
  }

  // ---- split-K MFMA: inp(16x32) = A(16x4096) @ M(4096x32); wave w owns K-chunk of 512 ----
  fx4 acc0 = {0.f, 0.f, 0.f, 0.f}, acc1 = {0.f, 0.f, 0.f, 0.f};
  {
    const unsigned short* Ap = Abf  + (size_t)(row0 + l15) * N_NODES + wave * 512 + quad * 8;
    const unsigned short* B0 = MtIn + (size_t)l15 * N_NODES        + wave * 512 + quad * 8;
    const unsigned short* B1 = MtIn + (size_t)(16 + l15) * N_NODES + wave * 512 + quad * 8;
#pragma unroll
    for (int kk = 0; kk < 16; ++kk) {
      bf16x8 a  = *(const bf16x8*)(Ap + kk * 32);
      bf16x8 b0 = *(const bf16x8*)(B0 + kk * 32);
      bf16x8 b1 = *(const bf16x8*)(B1 + kk * 32);
      acc0 = __builtin_amdgcn_mfma_f32_16x16x32_bf16(a, b0, acc0, 0, 0, 0);
      acc1 = __builtin_amdgcn_mfma_f32_16x16x32_bf16(a, b1, acc1, 0, 0, 0);
    }
  }
  // C-layout: row = quad*4+reg, col = l15 (m89/m91-verified)
#pragma unroll
  for (int r = 0; r < 4; ++r) {
    red[(wave * 16 + quad * 4 + r) * 33 + l15]      = acc0[r];
    red[(wave * 16 + quad * 4 + r) * 33 + 16 + l15] = acc1[r];
  }
  __syncthreads();

  // reduce 8 partials -> inp (bf16, A-frag layout)
  { int m = tid >> 5, n = tid & 31;
    float s = 0.f;
#pragma unroll
    for (int w = 0; w < 8; ++w) s += red[(w * 16 + m) * 33 + n];
    inpB[m * 48 + n] = f2bf(s);
  }
  __syncthreads();

  // ---- gates(16x128) = inp@Wih^T + h@Whh^T + b ; wave w owns gate cols [16w,16w+16) ----
  {
    int g = (wave << 4) + l15;
    bf16x8 aI = *(const bf16x8*)(inpB + l15 * 48 + quad * 8);
    bf16x8 aH = *(const bf16x8*)(hB   + l15 * 48 + quad * 8);
    bf16x8 bI = *(const bf16x8*)(WihB + g * 32 + quad * 8);   // B[k][n]=Wih[g][k], k-contig 16B
    bf16x8 bH = *(const bf16x8*)(WhhB + g * 32 + quad * 8);
    fx4 gacc = {0.f, 0.f, 0.f, 0.f};
    gacc = __builtin_amdgcn_mfma_f32_16x16x32_bf16(aI, bI, gacc, 0, 0, 0);
    gacc = __builtin_amdgcn_mfma_f32_16x16x32_bf16(aH, bH, gacc, 0, 0, 0);
    float bias = b_ih[g] + b_hh[g];
#pragma unroll
    for (int r = 0; r < 4; ++r) gatesLds[(quad * 4 + r) * 132 + g] = gacc[r] + bias;
  }
  __syncthreads();

  // ---- LSTM cell elementwise (fp32 state) ----
  { int r = tid >> 5, k = tid & 31;
    float gi = gatesLds[r * 132 + k];
    float gf = gatesLds[r * 132 + 32 + k];
    float gg = gatesLds[r * 132 + 64 + k];
    float go = gatesLds[r * 132 + 96 + k];
    float i_ = 1.f / (1.f + __expf(-gi));
    float f_ = 1.f / (1.f + __expf(-gf));
    float g_ = tanhf(gg);
    float o_ = 1.f / (1.f + __expf(-go));
    size_t idx = (size_t)(row0 + r) * H_DIM + k;
    float cn = f_ * c[idx] + i_ * g_;
    float hn = o_ * tanhf(cn);
    c[idx] = cn;
    h[idx] = hn;
    hnB[r * 48 + k] = f2bf(hn);
    cnB[r * 48 + k] = f2bf(cn);
    if (last) gatesLds[r * 132 + k] = hn * Wfc[k];   // slot only re-read by this thread's row sum
  }
  __syncthreads();

  if (last) {
    if (tid < 16) {
      float s = b_fc[0];
#pragma unroll
      for (int k = 0; k < 32; ++k) s += gatesLds[tid * 132 + k];
      out[row0 + tid] = s;
    }
  } else {
    // ---- M_next = h_new@Wh + c_new@Wc + x@Wx (waves 0,1) ----
    if (wave < 2) {
      int n = (wave << 4) + l15;
      bf16x8 aH = *(const bf16x8*)(hnB + l15 * 48 + quad * 8);
      bf16x8 aC = *(const bf16x8*)(cnB + l15 * 48 + quad * 8);
      bf16x8 bH = *(const bf16x8*)(WhT + n * 32 + quad * 8);
      bf16x8 bC = *(const bf16x8*)(WcT + n * 32 + quad * 8);
      fx4 m4 = {0.f, 0.f, 0.f, 0.f};
      m4 = __builtin_amdgcn_mfma_f32_16x16x32_bf16(aH, bH, m4, 0, 0, 0);
      m4 = __builtin_amdgcn_mfma_f32_16x16x32_bf16(aC, bC, m4, 0, 0, 0);
#pragma unroll
      for (int r = 0; r < 4; ++r) {
        int m = quad * 4 + r;
        float xs = m4[r];
#pragma unroll
        for (int f = 0; f < F_INPUT; ++f) xs += xLds[m * 8 + f] * Wx[f * H_DIM + n];
        MnB[m * 48 + n] = f2bf(xs);
      }
    }
    __syncthreads();
    // transposed coalesced write: Mt_next[n][row0+r]
    { int k = tid >> 4, rr = tid & 15;
      MtOut[(size_t)k * N_NODES + row0 + rr] = MnB[rr * 48 + k]; }
  }
}

extern "C" void kernel_launch(void* const* d_in, const int* in_sizes, int n_in,
                              void* d_out, int out_size, void* d_ws, size_t ws_size,
                              hipStream_t stream) {
  (void)in_sizes; (void)n_in; (void)out_size; (void)ws_size;
  const float* X   = (const float*)d_in[0];
  const float* A   = (const float*)d_in[1];
  const float* Wx  = (const float*)d_in[2];
  const float* Wh  = (const float*)d_in[3];
  const float* Wc  = (const float*)d_in[4];
  const float* Wih = (const float*)d_in[5];
  const float* Whh = (const float*)d_in[6];
  const float* bih = (const float*)d_in[7];
  const float* bhh = (const float*)d_in[8];
  const float* Wfc = (const float*)d_in[9];
  const float* bfc = (const float*)d_in[10];
  float* out = (float*)d_out;

  char* ws = (char*)d_ws;
  unsigned short* Abf  = (unsigned short*)ws; ws += (size_t)N_NODES * N_NODES * 2;  // 32 MiB
  unsigned short* Mt0  = (unsigned short*)ws; ws += (size_t)N_NODES * H_DIM * 2;
  unsigned short* Mt1  = (unsigned short*)ws; ws += (size_t)N_NODES * H_DIM * 2;
  float* h             = (float*)ws;          ws += (size_t)N_NODES * H_DIM * 4;
  float* c             = (float*)ws;          ws += (size_t)N_NODES * H_DIM * 4;
  unsigned short* WihB = (unsigned short*)ws; ws += 128 * 32 * 2;
  unsigned short* WhhB = (unsigned short*)ws; ws += 128 * 32 * 2;
  unsigned short* WhT  = (unsigned short*)ws; ws += 32 * 32 * 2;
  unsigned short* WcT  = (unsigned short*)ws; ws += 32 * 32 * 2;

  hipLaunchKernelGGL(k_convA, dim3(2048), dim3(256), 0, stream, A, Abf);
  hipLaunchKernelGGL(k_init, dim3(512), dim3(256), 0, stream,
                     X, Wx, Wih, Whh, Wh, Wc, Mt0, h, c, WihB, WhhB, WhT, WcT);

  for (int t = 0; t < ROLLS; ++t) {
    const unsigned short* Mi = (t & 1) ? Mt1 : Mt0;
    unsigned short* Mo       = (t & 1) ? Mt0 : Mt1;
    int tn = (t + 1 < ROLLS) ? (t + 1) : 0;               // x_{t+1}; unused on last step
    const float* Xn = X + (size_t)tn * N_NODES * F_INPUT;
    hipLaunchKernelGGL(k_step, dim3(256), dim3(512), 0, stream,
                       Abf, Mi, Mo, h, c, WihB, WhhB, WhT, WcT,
                       Xn, Wx, bih, bhh, Wfc, bfc, out, (t == ROLLS - 1) ? 1 : 0);
  }
}